// Round 8
// baseline (440.269 us; speedup 1.0000x reference)
//
#include <hip/hip_runtime.h>
#include <hip/hip_bf16.h>
#include <math.h>

#define BB 2
#define NN 4096
#define DD 512
#define FF 257
#define FP 288            // padded complex freq bins
#define KK2 (2*FP)        // 576 bf16 along K for gram
#define NT 528            // 32*33/2 upper-tri 128x128 tiles per batch
#define PI_F 3.14159265358979323846f
#define CEXP 0.72134752044f   // 0.5 * log2(e): exp(s/2) == exp2(s*CEXP)

typedef __attribute__((ext_vector_type(4))) float f32x4;
typedef __attribute__((ext_vector_type(8))) short bf16x8;
typedef unsigned int u32;
typedef unsigned short u16;

// ---- workspace layout (bytes) ----
#define MT_OFF  0u          // bf16 Mt[576][512]            = 589,824 (pad to 1,052,672)
#define XF_OFF  1052672u    // bf16 xhat/Xf[8192][576]      = 9,437,184
#define XB_OFF  10489856u   // bf16 xb[8192][512]           = 8,388,608
#define NR_OFF  (XB_OFF + 8388608u)   // f32 norms[8192] = 32,768
#define L_OFF   (NR_OFF + 32768u)     // f32 l[8192]     = 32,768
#define XT_OFF  77598720u   // bf16 xbT[2][512][4096]       = 8,388,608

#define AS1 __attribute__((address_space(1)))
#define AS3 __attribute__((address_space(3)))

static __device__ __forceinline__ void gl2lds(const u16* g, u16* l) {
    __builtin_amdgcn_global_load_lds((const AS1 u32*)(unsigned long long)g,
                                     (AS3 u32*)(unsigned)(unsigned long long)l,
                                     16, 0, 0);
}

static __device__ __forceinline__ unsigned short f2bf(float f) {
    unsigned int u = __float_as_uint(f);
    unsigned int r = (u + 0x7fffu + ((u >> 16) & 1u)) >> 16;   // RNE
    return (unsigned short)r;
}
static __device__ __forceinline__ float bf2f(unsigned short s) {
    return __uint_as_float(((unsigned int)s) << 16);
}

// (re,im) bf16 pair per dword -> (im, -re)
static __device__ __forceinline__ bf16x8 conj_swap(bf16x8 a) {
    union { bf16x8 v; u32 u[4]; } s, d;
    s.v = a;
#pragma unroll
    for (int i = 0; i < 4; ++i) {
        u32 w = s.u[i];
        d.u[i] = ((w >> 16) | (w << 16)) ^ 0x80000000u;
    }
    return d.v;
}

// ---------------------------------------------------------------------------
// zero Mt pad rows [514,576), norms[8192], l[8192]
__global__ __launch_bounds__(256) void k_zero(float* __restrict__ norms,
                                              float* __restrict__ l,
                                              u16* __restrict__ Mt) {
    int i = blockIdx.x * 256 + threadIdx.x;        // grid 124*256 = 31744
    if (i < 8192) { norms[i] = 0.f; l[i] = 0.f; }
    Mt[514 * 512 + i] = 0;                         // 62 rows * 512 = 31744
}

// ---------------------------------------------------------------------------
// Mt[2g][d] = Re sum_f W[g,f] e^{-2pi i f d/512}; Mt[2g+1][d] = Im ...  (bf16)
__global__ __launch_bounds__(512) void k_build_Mt(const float* __restrict__ W,
                                                  u16* __restrict__ Mt) {
    __shared__ float twr[512], twi[512], wrow[FF];
    const int g = blockIdx.x;          // 0..256
    const int d = threadIdx.x;         // 0..511
    {
        float s, c;
        sincosf(-(2.0f * PI_F / 512.0f) * (float)d, &s, &c);
        twr[d] = c; twi[d] = s;
    }
    for (int f = d; f < FF; f += 512) wrow[f] = W[g * FF + f];
    __syncthreads();
    float re = 0.f, im = 0.f;
    for (int f = 0; f < FF; ++f) {
        float w = wrow[f];
        int k = (f * d) & 511;
        re = fmaf(w, twr[k], re);
        im = fmaf(w, twi[k], im);
    }
    Mt[(size_t)(2 * g) * 512 + d]     = f2bf(re);
    Mt[(size_t)(2 * g + 1) * 512 + d] = f2bf(im);
}

// ---------------------------------------------------------------------------
// xb = bf16(x), flat [8192*512]
__global__ __launch_bounds__(256) void k_xcast(const float* __restrict__ x,
                                               u16* __restrict__ xb) {
    const size_t i = ((size_t)blockIdx.x * 256 + threadIdx.x) * 8;
    float4 a = *(const float4*)(x + i);
    float4 b = *(const float4*)(x + i + 4);
    union { u16 h[8]; uint4 q; } o;
    o.h[0] = f2bf(a.x); o.h[1] = f2bf(a.y); o.h[2] = f2bf(a.z); o.h[3] = f2bf(a.w);
    o.h[4] = f2bf(b.x); o.h[5] = f2bf(b.y); o.h[6] = f2bf(b.z); o.h[7] = f2bf(b.w);
    *(uint4*)(xb + i) = o.q;
}

// ---------------------------------------------------------------------------
// xhat[r][g2] = sum_d xb[r][d]*Mt[g2][d], bf16 out; norms[r] += row sumsq.
__global__ __launch_bounds__(256) void k_proj_mfma(const u16* __restrict__ xb,
                                                   const u16* __restrict__ Mt,
                                                   u16* __restrict__ xhat,
                                                   float* __restrict__ norms) {
    __shared__ u16 As[128 * 64];
    __shared__ u16 Bs[64 * 64];
    const int prow = blockIdx.y * 128;
    const int gcol = blockIdx.x * 64;
    const int tid = threadIdx.x;
    const int lane = tid & 63;
    const int wave = tid >> 6;
    const int wr = wave * 32;
    const int fr = lane & 15;
    const int q  = lane >> 4;
    const int sw = lane & 7;

    const u16* __restrict__ Arow = xb + (size_t)prow * DD;
    const u16* __restrict__ Brow = Mt + (size_t)gcol * DD;

    const int cs0 = (q ^ sw) * 8;
    const int cs1 = ((4 + q) ^ sw) * 8;

    f32x4 acc[2][4];
#pragma unroll
    for (int m = 0; m < 2; ++m)
#pragma unroll
        for (int n = 0; n < 4; ++n) acc[m][n] = (f32x4)0.f;

    int rA[2], rB[4];
#pragma unroll
    for (int m = 0; m < 2; ++m) rA[m] = (wr + m * 16 + fr) * 64;
#pragma unroll
    for (int n = 0; n < 4; ++n) rB[n] = (n * 16 + fr) * 64;

    for (int kc = 0; kc < DD / 64; ++kc) {
        const int k0 = kc * 64;
        __syncthreads();
#pragma unroll
        for (int it = 0; it < 4; ++it) {          // A: 128 rows x 8 chunks
            int e = tid + it * 256;
            int row = e >> 3, ch = e & 7;
            gl2lds(Arow + (size_t)row * DD + k0 + (ch ^ (row & 7)) * 8, &As[e * 8]);
        }
#pragma unroll
        for (int it = 0; it < 2; ++it) {          // B: 64 rows x 8 chunks
            int e = tid + it * 256;
            int row = e >> 3, ch = e & 7;
            gl2lds(Brow + (size_t)row * DD + k0 + (ch ^ (row & 7)) * 8, &Bs[e * 8]);
        }
        __syncthreads();
#pragma unroll
        for (int kk = 0; kk < 2; ++kk) {
            const int cs = kk ? cs1 : cs0;
            bf16x8 av[2], bv[4];
#pragma unroll
            for (int m = 0; m < 2; ++m) av[m] = *(const bf16x8*)&As[rA[m] + cs];
#pragma unroll
            for (int n = 0; n < 4; ++n) bv[n] = *(const bf16x8*)&Bs[rB[n] + cs];
#pragma unroll
            for (int m = 0; m < 2; ++m)
#pragma unroll
                for (int n = 0; n < 4; ++n)
                    acc[m][n] = __builtin_amdgcn_mfma_f32_16x16x32_bf16(av[m], bv[n], acc[m][n], 0, 0, 0);
        }
    }

#pragma unroll
    for (int m = 0; m < 2; ++m) {
#pragma unroll
        for (int reg = 0; reg < 4; ++reg) {
            const int r = prow + wr + m * 16 + q * 4 + reg;
            u16* __restrict__ rp = xhat + (size_t)r * KK2 + gcol + fr;
            float sq = 0.f;
#pragma unroll
            for (int n = 0; n < 4; ++n) {
                float v = acc[m][n][reg];
                rp[n * 16] = f2bf(v);
                sq = fmaf(v, v, sq);
            }
            sq += __shfl_xor(sq, 1);
            sq += __shfl_xor(sq, 2);
            sq += __shfl_xor(sq, 4);
            sq += __shfl_xor(sq, 8);
            if (fr == 0) atomicAdd(&norms[r], sq);
        }
    }
}

// ---------------------------------------------------------------------------
// Xf[row][*] *= rsqrt(norms[row] + eps)   (in place, u32 = 2 bf16)
__global__ __launch_bounds__(256) void k_normalize(u32* __restrict__ Xf,
                                                   const float* __restrict__ norms) {
    const int row = blockIdx.x * 8 + (threadIdx.x >> 5);
    const int l = threadIdx.x & 31;
    const float rn = rsqrtf(norms[row] + 1e-8f);
    u32* __restrict__ p = Xf + (size_t)row * FP;
#pragma unroll
    for (int u = 0; u < 9; ++u) {
        u32 w = p[u * 32 + l];
        float lo = bf2f((u16)(w & 0xffffu)) * rn;
        float hi = bf2f((u16)(w >> 16)) * rn;
        p[u * 32 + l] = (u32)f2bf(lo) | ((u32)f2bf(hi) << 16);
    }
}

// ---------------------------------------------------------------------------
// S = |Xn Xn^H| (tri-tiles + mirror), also accumulates l[row] = sum exp(S/2)
// (no max needed: S in [0,1]). trs LDS aliased onto dead Af/Bf.
__global__ __launch_bounds__(256) void k_gram_mfma(const u16* __restrict__ Xf,
                                                   float* __restrict__ Sout,
                                                   float* __restrict__ lsum) {
    __shared__ __align__(16) char gsm[32768];
    u16* Af = (u16*)gsm;
    u16* Bf = (u16*)(gsm + 16384);
    float (*trs)[129] = (float (*)[129])gsm;     // 16512B, reuses Af(+128B of Bf)

    int i = (int)blockIdx.x;
    int b = 0;
    if (i >= NT) { b = 1; i -= NT; }
    int a = 0;
    while (i >= 32 - a) { i -= 32 - a; ++a; }
    const int brow = a * 128;
    const int bcol = (a + i) * 128;

    const int tid = threadIdx.x;
    const int lane = tid & 63;
    const int wave = tid >> 6;
    const int wr = (wave >> 1) * 64;
    const int wc = (wave & 1) * 64;
    const int fr = lane & 15;
    const int q  = lane >> 4;
    const int sw = lane & 7;

    const u16* __restrict__ Arow = Xf + (size_t)(b * NN + brow) * KK2;
    const u16* __restrict__ Brow = Xf + (size_t)(b * NN + bcol) * KK2;

    int srow[4], soff[4];
#pragma unroll
    for (int it = 0; it < 4; ++it) {
        int e = tid + it * 256;
        int row = e >> 3, ch = e & 7;
        srow[it] = row;
        soff[it] = (ch ^ (row & 7)) * 8;
    }
    const int cs0 = (q ^ sw) * 8;
    const int cs1 = ((4 + q) ^ sw) * 8;

    f32x4 acc_re[4][4], acc_im[4][4];
#pragma unroll
    for (int m = 0; m < 4; ++m)
#pragma unroll
        for (int n = 0; n < 4; ++n) {
            acc_re[m][n] = (f32x4)0.f;
            acc_im[m][n] = (f32x4)0.f;
        }

    int rA[4], rB[4];
#pragma unroll
    for (int m = 0; m < 4; ++m) rA[m] = (wr + m * 16 + fr) * 64;
#pragma unroll
    for (int n = 0; n < 4; ++n) rB[n] = (wc + n * 16 + fr) * 64;

    for (int kc = 0; kc < KK2 / 64; ++kc) {
        const int k0 = kc * 64;
        __syncthreads();
#pragma unroll
        for (int it = 0; it < 4; ++it) {
            int e = tid + it * 256;
            gl2lds(Arow + (size_t)srow[it] * KK2 + k0 + soff[it], &Af[e * 8]);
            gl2lds(Brow + (size_t)srow[it] * KK2 + k0 + soff[it], &Bf[e * 8]);
        }
        __syncthreads();
#pragma unroll
        for (int kk = 0; kk < 2; ++kk) {
            const int cs = kk ? cs1 : cs0;
            bf16x8 av[4], bv[4], gv[4];
#pragma unroll
            for (int m = 0; m < 4; ++m) av[m] = *(const bf16x8*)&Af[rA[m] + cs];
#pragma unroll
            for (int n = 0; n < 4; ++n) bv[n] = *(const bf16x8*)&Bf[rB[n] + cs];
#pragma unroll
            for (int m = 0; m < 4; ++m) gv[m] = conj_swap(av[m]);
#pragma unroll
            for (int m = 0; m < 4; ++m)
#pragma unroll
                for (int n = 0; n < 4; ++n) {
                    acc_re[m][n] = __builtin_amdgcn_mfma_f32_16x16x32_bf16(av[m], bv[n], acc_re[m][n], 0, 0, 0);
                    acc_im[m][n] = __builtin_amdgcn_mfma_f32_16x16x32_bf16(gv[m], bv[n], acc_im[m][n], 0, 0, 0);
                }
        }
    }

    float* __restrict__ Sb = Sout + (size_t)b * NN * NN;
    float* __restrict__ lb = lsum + (size_t)b * NN;
    // direct store + l accumulation
#pragma unroll
    for (int m = 0; m < 4; ++m) {
#pragma unroll
        for (int reg = 0; reg < 4; ++reg) {
            int r = brow + wr + m * 16 + q * 4 + reg;
            float* __restrict__ rp = Sb + (size_t)r * NN + bcol + wc + fr;
            float psum = 0.f;
#pragma unroll
            for (int n = 0; n < 4; ++n) {
                float re = acc_re[m][n][reg], im = acc_im[m][n][reg];
                float s = sqrtf(fmaf(re, re, im * im));
                rp[n * 16] = s;
                psum += exp2f(s * CEXP);
            }
            psum += __shfl_xor(psum, 1);
            psum += __shfl_xor(psum, 2);
            psum += __shfl_xor(psum, 4);
            psum += __shfl_xor(psum, 8);
            if (fr == 0) atomicAdd(&lb[r], psum);
        }
    }
    if (brow == bcol) return;

    // mirror store via LDS transpose (trs aliases Af/Bf — dead after K-loop)
#pragma unroll
    for (int p = 0; p < 4; ++p) {
        __syncthreads();
        if ((wave >> 1) == (p >> 1)) {
            const int mbase = (p & 1) * 2;
#pragma unroll
            for (int mm = 0; mm < 2; ++mm) {
                const int m = mbase + mm;
                const int i0 = mm * 16 + q * 4;
#pragma unroll
                for (int reg = 0; reg < 4; ++reg) {
#pragma unroll
                    for (int n = 0; n < 4; ++n) {
                        float re = acc_re[m][n][reg], im = acc_im[m][n][reg];
                        trs[i0 + reg][wc + n * 16 + fr] = sqrtf(fmaf(re, re, im * im));
                    }
                }
            }
        }
        __syncthreads();
        const int j0 = (tid & 7) * 4;
#pragma unroll
        for (int u = 0; u < 4; ++u) {
            const int mr = u * 32 + (tid >> 3);
            float4 v;
            v.x = trs[j0 + 0][mr];
            v.y = trs[j0 + 1][mr];
            v.z = trs[j0 + 2][mr];
            v.w = trs[j0 + 3][mr];
            *(float4*)(Sb + (size_t)(bcol + mr) * NN + brow + p * 32 + j0) = v;
            float ps = exp2f(v.x * CEXP) + exp2f(v.y * CEXP)
                     + exp2f(v.z * CEXP) + exp2f(v.w * CEXP);
            ps += __shfl_xor(ps, 1);
            ps += __shfl_xor(ps, 2);
            ps += __shfl_xor(ps, 4);
            if ((tid & 7) == 0) atomicAdd(&lb[bcol + mr], ps);
        }
    }
}

// ---------------------------------------------------------------------------
// xbT[b][d][t] = bf16(x[b][t][d])  (64x64 tiles through LDS)
__global__ __launch_bounds__(256) void k_xpose(const float* __restrict__ x,
                                               u16* __restrict__ xbT) {
    __shared__ u16 st[64][72];
    const int b = blockIdx.z;
    const int t0 = blockIdx.x * 64;
    const int d0 = blockIdx.y * 64;
    const int tid = threadIdx.x;
#pragma unroll
    for (int u = 0; u < 4; ++u) {
        int idx = tid + u * 256;               // 0..1023
        int tl = idx >> 4, d4 = (idx & 15) * 4;
        float4 v = *(const float4*)(x + ((size_t)(b * NN) + t0 + tl) * DD + d0 + d4);
        st[tl][d4 + 0] = f2bf(v.x);
        st[tl][d4 + 1] = f2bf(v.y);
        st[tl][d4 + 2] = f2bf(v.z);
        st[tl][d4 + 3] = f2bf(v.w);
    }
    __syncthreads();
#pragma unroll
    for (int u = 0; u < 2; ++u) {
        int e = tid + u * 256;                 // 0..511
        int dl = e >> 3, t8 = (e & 7) * 8;
        union { u16 h[8]; uint4 q; } o;
#pragma unroll
        for (int j = 0; j < 8; ++j) o.h[j] = st[t8 + j][dl];
        *(uint4*)(xbT + ((size_t)(b * DD) + d0 + dl) * NN + t0 + t8) = o.q;
    }
}

// ---------------------------------------------------------------------------
// Fused: P = exp(S/2) on the fly (reg-staged A), O = P @ x^T via MFMA,
// mixed = O/l, h = 0.7x + 0.3*mixed, LayerNorm -> out.
// BM=32 rows/block, BN=512 (full D, split 128/wave), BK=64. Grid (NN/32, BB).
__global__ __launch_bounds__(256) void k_mixed_fused(const float* __restrict__ S,
                                                     const float* __restrict__ lsum,
                                                     const u16* __restrict__ xbT,
                                                     const float* __restrict__ x,
                                                     const float* __restrict__ gamma,
                                                     const float* __restrict__ beta,
                                                     float* __restrict__ out) {
    __shared__ __align__(16) u16 Bs[DD * 64];      // 64KB
    __shared__ __align__(16) u16 As[32 * 64];      // 4KB
    __shared__ float red[32][8];
    const int b = blockIdx.y;
    const int t0 = blockIdx.x * 32;
    const int tid = threadIdx.x;
    const int lane = tid & 63;
    const int wave = tid >> 6;
    const int fr = lane & 15;
    const int q  = lane >> 4;
    const int sw = lane & 7;
    const int dcol = wave * 128;

    const float* __restrict__ Srow = S + ((size_t)b * NN + t0) * NN;
    const u16* __restrict__ Brow = xbT + (size_t)b * DD * NN;

    const int cs0 = (q ^ sw) * 8;
    const int cs1 = ((4 + q) ^ sw) * 8;

    // A staging map: thread -> (row 0..31, chunk 0..7)
    const int ar = tid >> 3;
    const int ach = tid & 7;
    const float* __restrict__ aSrc = Srow + (size_t)ar * NN + ach * 8;
    u16* __restrict__ aDst = As + ar * 64 + (ach ^ (ar & 7)) * 8;

    f32x4 acc[2][8];
#pragma unroll
    for (int m = 0; m < 2; ++m)
#pragma unroll
        for (int n = 0; n < 8; ++n) acc[m][n] = (f32x4)0.f;

    int rA[2], rB[8];
#pragma unroll
    for (int m = 0; m < 2; ++m) rA[m] = (m * 16 + fr) * 64;
#pragma unroll
    for (int n = 0; n < 8; ++n) rB[n] = (dcol + n * 16 + fr) * 64;

    for (int kc = 0; kc < NN / 64; ++kc) {
        const int k0 = kc * 64;
        __syncthreads();
#pragma unroll
        for (int it = 0; it < 16; ++it) {       // B: 512 rows x 8 chunks
            int e = tid + it * 256;
            int row = e >> 3, ch = e & 7;
            gl2lds(Brow + (size_t)row * NN + k0 + (ch ^ (row & 7)) * 8, &Bs[e * 8]);
        }
        {   // A: load f32 S, exp2, pack bf16, swizzled ds_write
            float4 a0 = *(const float4*)(aSrc + k0);
            float4 a1 = *(const float4*)(aSrc + k0 + 4);
            union { u16 h[8]; uint4 v; } pk;
            pk.h[0] = f2bf(exp2f(a0.x * CEXP));
            pk.h[1] = f2bf(exp2f(a0.y * CEXP));
            pk.h[2] = f2bf(exp2f(a0.z * CEXP));
            pk.h[3] = f2bf(exp2f(a0.w * CEXP));
            pk.h[4] = f2bf(exp2f(a1.x * CEXP));
            pk.h[5] = f2bf(exp2f(a1.y * CEXP));
            pk.h[6] = f2bf(exp2f(a1.z * CEXP));
            pk.h[7] = f2bf(exp2f(a1.w * CEXP));
            *(uint4*)aDst = pk.v;
        }
        __syncthreads();
#pragma unroll
        for (int kk = 0; kk < 2; ++kk) {
            const int cs = kk ? cs1 : cs0;
            bf16x8 av[2], bv[8];
#pragma unroll
            for (int m = 0; m < 2; ++m) av[m] = *(const bf16x8*)&As[rA[m] + cs];
#pragma unroll
            for (int n = 0; n < 8; ++n) bv[n] = *(const bf16x8*)&Bs[rB[n] + cs];
#pragma unroll
            for (int m = 0; m < 2; ++m)
#pragma unroll
                for (int n = 0; n < 8; ++n)
                    acc[m][n] = __builtin_amdgcn_mfma_f32_16x16x32_bf16(av[m], bv[n], acc[m][n], 0, 0, 0);
        }
    }

    // epilogue: scale by 1/l, blend with x, LayerNorm
    __syncthreads();
#pragma unroll
    for (int m = 0; m < 2; ++m) {
#pragma unroll
        for (int reg = 0; reg < 4; ++reg) {
            const int r = m * 16 + q * 4 + reg;
            const float rinv = 1.0f / lsum[(size_t)b * NN + t0 + r];
            const float* __restrict__ xrow = x + ((size_t)b * NN + t0 + r) * DD;
            float sh = 0.f, sh2 = 0.f;
#pragma unroll
            for (int n = 0; n < 8; ++n) {
                float xv = xrow[dcol + n * 16 + fr];
                float h = fmaf(0.3f * rinv, acc[m][n][reg], 0.7f * xv);
                acc[m][n][reg] = h;
                sh += h;
                sh2 = fmaf(h, h, sh2);
            }
            sh += __shfl_xor(sh, 1);  sh2 += __shfl_xor(sh2, 1);
            sh += __shfl_xor(sh, 2);  sh2 += __shfl_xor(sh2, 2);
            sh += __shfl_xor(sh, 4);  sh2 += __shfl_xor(sh2, 4);
            sh += __shfl_xor(sh, 8);  sh2 += __shfl_xor(sh2, 8);
            if (fr == 0) { red[r][wave * 2] = sh; red[r][wave * 2 + 1] = sh2; }
        }
    }
    __syncthreads();
#pragma unroll
    for (int m = 0; m < 2; ++m) {
#pragma unroll
        for (int reg = 0; reg < 4; ++reg) {
            const int r = m * 16 + q * 4 + reg;
            const float s1 = (red[r][0] + red[r][2]) + (red[r][4] + red[r][6]);
            const float s2 = (red[r][1] + red[r][3]) + (red[r][5] + red[r][7]);
            const float mu = s1 * (1.0f / DD);
            const float var = s2 * (1.0f / DD) - mu * mu;
            const float rstd = rsqrtf(var + 1e-5f);
            float* __restrict__ orow = out + ((size_t)b * NN + t0 + r) * DD;
#pragma unroll
            for (int n = 0; n < 8; ++n) {
                const int col = dcol + n * 16 + fr;
                orow[col] = fmaf((acc[m][n][reg] - mu) * rstd, gamma[col], beta[col]);
            }
        }
    }
}

// ---------------------------------------------------------------------------
extern "C" void kernel_launch(void* const* d_in, const int* in_sizes, int n_in,
                              void* d_out, int out_size, void* d_ws, size_t ws_size,
                              hipStream_t stream) {
    const float* x     = (const float*)d_in[0];
    const float* Wspec = (const float*)d_in[1];
    const float* gamma = (const float*)d_in[2];
    const float* beta  = (const float*)d_in[3];
    float* out  = (float*)d_out;                       // [B][N][D]
    float* Sout = out + (size_t)BB * NN * DD;          // [B][N][N]

    char* ws = (char*)d_ws;
    u16*   Mt    = (u16*)(ws + MT_OFF);
    u16*   Xf    = (u16*)(ws + XF_OFF);       // xhat, then normalized Xf
    u32*   XfW   = (u32*)(ws + XF_OFF);
    u16*   xb    = (u16*)(ws + XB_OFF);
    float* norms = (float*)(ws + NR_OFF);
    float* lsum  = (float*)(ws + L_OFF);
    u16*   xbT   = (u16*)(ws + XT_OFF);

    hipLaunchKernelGGL(k_zero, dim3(124), dim3(256), 0, stream, norms, lsum, Mt);
    hipLaunchKernelGGL(k_build_Mt, dim3(257), dim3(512), 0, stream, Wspec, Mt);
    hipLaunchKernelGGL(k_xcast, dim3(2048), dim3(256), 0, stream, x, xb);
    hipLaunchKernelGGL(k_proj_mfma, dim3(KK2 / 64, (BB * NN) / 128), dim3(256), 0, stream,
                       xb, Mt, Xf, norms);
    hipLaunchKernelGGL(k_normalize, dim3(BB * NN / 8), dim3(256), 0, stream, XfW, norms);
    hipLaunchKernelGGL(k_gram_mfma, dim3(BB * NT), dim3(256), 0, stream, Xf, Sout, lsum);
    hipLaunchKernelGGL(k_xpose, dim3(NN / 64, DD / 64, BB), dim3(256), 0, stream, x, xbT);
    hipLaunchKernelGGL(k_mixed_fused, dim3(NN / 32, BB), dim3(256), 0, stream,
                       Sout, lsum, xbT, x, gamma, beta, out);
}

// Round 10
// 413.086 us; speedup vs baseline: 1.0658x; 1.0658x over previous
//
#include <hip/hip_runtime.h>
#include <hip/hip_bf16.h>
#include <math.h>

#define BB 2
#define NN 4096
#define DD 512
#define FF 257
#define FP 288            // padded complex freq bins
#define KK2 (2*FP)        // 576 bf16 along K for gram
#define NT 528            // 32*33/2 upper-tri 128x128 tiles per batch
#define KS 4              // split-K factor for mixed
#define PI_F 3.14159265358979323846f
#define CEXP 0.72134752044f   // 0.5 * log2(e): exp(s/2) == exp2(s*CEXP)

typedef __attribute__((ext_vector_type(4))) float f32x4;
typedef __attribute__((ext_vector_type(8))) short bf16x8;
typedef unsigned int u32;
typedef unsigned short u16;

// ---- workspace layout (bytes) ----
#define MT_OFF  0u          // bf16 Mt[576][512] = 589,824 (pad to 1,052,672)
#define XF_OFF  1052672u    // bf16 xhat/Xf[8192][576] = 9,437,184
#define SS_OFF  10489856u   // bf16 Ssoft[2][4096][4096] = 67,108,864
                            //   (pre-softmax aliased: xb bf16[8192][512] + norms)
#define NR_OFF  (SS_OFF + 8388608u)   // f32 norms[8192]
#define XT_OFF  77598720u   // bf16 xbT[2][512][4096] = 8,388,608
#define MX_OFF  85987328u   // f32 mixed[2][4096][512] = 16,777,216 (end 102,764,544)
#define MX_BYTES 16777216u

#define AS1 __attribute__((address_space(1)))
#define AS3 __attribute__((address_space(3)))

static __device__ __forceinline__ void gl2lds(const u16* g, u16* l) {
    __builtin_amdgcn_global_load_lds((const AS1 u32*)(unsigned long long)g,
                                     (AS3 u32*)(unsigned)(unsigned long long)l,
                                     16, 0, 0);
}

static __device__ __forceinline__ unsigned short f2bf(float f) {
    unsigned int u = __float_as_uint(f);
    unsigned int r = (u + 0x7fffu + ((u >> 16) & 1u)) >> 16;   // RNE
    return (unsigned short)r;
}
static __device__ __forceinline__ float bf2f(unsigned short s) {
    return __uint_as_float(((unsigned int)s) << 16);
}

// (re,im) bf16 pair per dword -> (im, -re)
static __device__ __forceinline__ bf16x8 conj_swap(bf16x8 a) {
    union { bf16x8 v; u32 u[4]; } s, d;
    s.v = a;
#pragma unroll
    for (int i = 0; i < 4; ++i) {
        u32 w = s.u[i];
        d.u[i] = ((w >> 16) | (w << 16)) ^ 0x80000000u;
    }
    return d.v;
}

// ---------------------------------------------------------------------------
// zero Mt pad rows [514,576) and norms[8192]
__global__ __launch_bounds__(256) void k_zero(float* __restrict__ norms,
                                              u16* __restrict__ Mt) {
    int i = blockIdx.x * 256 + threadIdx.x;        // grid 124*256 = 31744
    if (i < 8192) norms[i] = 0.f;
    Mt[514 * 512 + i] = 0;                         // 62 rows * 512 = 31744
}

// ---------------------------------------------------------------------------
// Mt[2g][d] = Re sum_f W[g,f] e^{-2pi i f d/512}; Mt[2g+1][d] = Im ...  (bf16)
__global__ __launch_bounds__(512) void k_build_Mt(const float* __restrict__ W,
                                                  u16* __restrict__ Mt) {
    __shared__ float twr[512], twi[512], wrow[FF];
    const int g = blockIdx.x;          // 0..256
    const int d = threadIdx.x;         // 0..511
    {
        float s, c;
        sincosf(-(2.0f * PI_F / 512.0f) * (float)d, &s, &c);
        twr[d] = c; twi[d] = s;
    }
    for (int f = d; f < FF; f += 512) wrow[f] = W[g * FF + f];
    __syncthreads();
    float re = 0.f, im = 0.f;
    for (int f = 0; f < FF; ++f) {
        float w = wrow[f];
        int k = (f * d) & 511;
        re = fmaf(w, twr[k], re);
        im = fmaf(w, twi[k], im);
    }
    Mt[(size_t)(2 * g) * 512 + d]     = f2bf(re);
    Mt[(size_t)(2 * g + 1) * 512 + d] = f2bf(im);
}

// ---------------------------------------------------------------------------
// xb = bf16(x), flat [8192*512]
__global__ __launch_bounds__(256) void k_xcast(const float* __restrict__ x,
                                               u16* __restrict__ xb) {
    const size_t i = ((size_t)blockIdx.x * 256 + threadIdx.x) * 8;
    float4 a = *(const float4*)(x + i);
    float4 b = *(const float4*)(x + i + 4);
    union { u16 h[8]; uint4 q; } o;
    o.h[0] = f2bf(a.x); o.h[1] = f2bf(a.y); o.h[2] = f2bf(a.z); o.h[3] = f2bf(a.w);
    o.h[4] = f2bf(b.x); o.h[5] = f2bf(b.y); o.h[6] = f2bf(b.z); o.h[7] = f2bf(b.w);
    *(uint4*)(xb + i) = o.q;
}

// ---------------------------------------------------------------------------
// xhat[r][g2] = sum_d xb[r][d]*Mt[g2][d], bf16 out; norms[r] += row sumsq.
__global__ __launch_bounds__(256) void k_proj_mfma(const u16* __restrict__ xb,
                                                   const u16* __restrict__ Mt,
                                                   u16* __restrict__ xhat,
                                                   float* __restrict__ norms) {
    __shared__ u16 As[128 * 64];
    __shared__ u16 Bs[64 * 64];
    const int prow = blockIdx.y * 128;
    const int gcol = blockIdx.x * 64;
    const int tid = threadIdx.x;
    const int lane = tid & 63;
    const int wave = tid >> 6;
    const int wr = wave * 32;
    const int fr = lane & 15;
    const int q  = lane >> 4;
    const int sw = lane & 7;

    const u16* __restrict__ Arow = xb + (size_t)prow * DD;
    const u16* __restrict__ Brow = Mt + (size_t)gcol * DD;

    const int cs0 = (q ^ sw) * 8;
    const int cs1 = ((4 + q) ^ sw) * 8;

    f32x4 acc[2][4];
#pragma unroll
    for (int m = 0; m < 2; ++m)
#pragma unroll
        for (int n = 0; n < 4; ++n) acc[m][n] = (f32x4)0.f;

    int rA[2], rB[4];
#pragma unroll
    for (int m = 0; m < 2; ++m) rA[m] = (wr + m * 16 + fr) * 64;
#pragma unroll
    for (int n = 0; n < 4; ++n) rB[n] = (n * 16 + fr) * 64;

    for (int kc = 0; kc < DD / 64; ++kc) {
        const int k0 = kc * 64;
        __syncthreads();
#pragma unroll
        for (int it = 0; it < 4; ++it) {          // A: 128 rows x 8 chunks
            int e = tid + it * 256;
            int row = e >> 3, ch = e & 7;
            gl2lds(Arow + (size_t)row * DD + k0 + (ch ^ (row & 7)) * 8, &As[e * 8]);
        }
#pragma unroll
        for (int it = 0; it < 2; ++it) {          // B: 64 rows x 8 chunks
            int e = tid + it * 256;
            int row = e >> 3, ch = e & 7;
            gl2lds(Brow + (size_t)row * DD + k0 + (ch ^ (row & 7)) * 8, &Bs[e * 8]);
        }
        __syncthreads();
#pragma unroll
        for (int kk = 0; kk < 2; ++kk) {
            const int cs = kk ? cs1 : cs0;
            bf16x8 av[2], bv[4];
#pragma unroll
            for (int m = 0; m < 2; ++m) av[m] = *(const bf16x8*)&As[rA[m] + cs];
#pragma unroll
            for (int n = 0; n < 4; ++n) bv[n] = *(const bf16x8*)&Bs[rB[n] + cs];
#pragma unroll
            for (int m = 0; m < 2; ++m)
#pragma unroll
                for (int n = 0; n < 4; ++n)
                    acc[m][n] = __builtin_amdgcn_mfma_f32_16x16x32_bf16(av[m], bv[n], acc[m][n], 0, 0, 0);
        }
    }

#pragma unroll
    for (int m = 0; m < 2; ++m) {
#pragma unroll
        for (int reg = 0; reg < 4; ++reg) {
            const int r = prow + wr + m * 16 + q * 4 + reg;
            u16* __restrict__ rp = xhat + (size_t)r * KK2 + gcol + fr;
            float sq = 0.f;
#pragma unroll
            for (int n = 0; n < 4; ++n) {
                float v = acc[m][n][reg];
                rp[n * 16] = f2bf(v);
                sq = fmaf(v, v, sq);
            }
            sq += __shfl_xor(sq, 1);
            sq += __shfl_xor(sq, 2);
            sq += __shfl_xor(sq, 4);
            sq += __shfl_xor(sq, 8);
            if (fr == 0) atomicAdd(&norms[r], sq);
        }
    }
}

// ---------------------------------------------------------------------------
// Xf[row][*] *= rsqrt(norms[row] + eps)   (in place, u32 = 2 bf16)
__global__ __launch_bounds__(256) void k_normalize(u32* __restrict__ Xf,
                                                   const float* __restrict__ norms) {
    const int row = blockIdx.x * 8 + (threadIdx.x >> 5);
    const int l = threadIdx.x & 31;
    const float rn = rsqrtf(norms[row] + 1e-8f);
    u32* __restrict__ p = Xf + (size_t)row * FP;
#pragma unroll
    for (int u = 0; u < 9; ++u) {
        u32 w = p[u * 32 + l];
        float lo = bf2f((u16)(w & 0xffffu)) * rn;
        float hi = bf2f((u16)(w >> 16)) * rn;
        p[u * 32 + l] = (u32)f2bf(lo) | ((u32)f2bf(hi) << 16);
    }
}

// ---------------------------------------------------------------------------
// S = |Xn Xn^H|, symmetric: upper-tri+diag 128x128 tiles, mirror via LDS
// transpose (trs aliased onto dead Af/Bf). Epilogue = round-7 form (no exp).
__global__ __launch_bounds__(256) void k_gram_mfma(const u16* __restrict__ Xf,
                                                   float* __restrict__ Sout) {
    __shared__ __align__(16) char gsm[32768];
    u16* Af = (u16*)gsm;
    u16* Bf = (u16*)(gsm + 16384);
    float (*trs)[129] = (float (*)[129])gsm;     // reuses Af/Bf after K-loop

    int i = (int)blockIdx.x;
    int b = 0;
    if (i >= NT) { b = 1; i -= NT; }
    int a = 0;
    while (i >= 32 - a) { i -= 32 - a; ++a; }
    const int brow = a * 128;
    const int bcol = (a + i) * 128;

    const int tid = threadIdx.x;
    const int lane = tid & 63;
    const int wave = tid >> 6;
    const int wr = (wave >> 1) * 64;
    const int wc = (wave & 1) * 64;
    const int fr = lane & 15;
    const int q  = lane >> 4;
    const int sw = lane & 7;

    const u16* __restrict__ Arow = Xf + (size_t)(b * NN + brow) * KK2;
    const u16* __restrict__ Brow = Xf + (size_t)(b * NN + bcol) * KK2;

    int srow[4], soff[4];
#pragma unroll
    for (int it = 0; it < 4; ++it) {
        int e = tid + it * 256;
        int row = e >> 3, ch = e & 7;
        srow[it] = row;
        soff[it] = (ch ^ (row & 7)) * 8;
    }
    const int cs0 = (q ^ sw) * 8;
    const int cs1 = ((4 + q) ^ sw) * 8;

    f32x4 acc_re[4][4], acc_im[4][4];
#pragma unroll
    for (int m = 0; m < 4; ++m)
#pragma unroll
        for (int n = 0; n < 4; ++n) {
            acc_re[m][n] = (f32x4)0.f;
            acc_im[m][n] = (f32x4)0.f;
        }

    int rA[4], rB[4];
#pragma unroll
    for (int m = 0; m < 4; ++m) rA[m] = (wr + m * 16 + fr) * 64;
#pragma unroll
    for (int n = 0; n < 4; ++n) rB[n] = (wc + n * 16 + fr) * 64;

    for (int kc = 0; kc < KK2 / 64; ++kc) {
        const int k0 = kc * 64;
        __syncthreads();
#pragma unroll
        for (int it = 0; it < 4; ++it) {
            int e = tid + it * 256;
            gl2lds(Arow + (size_t)srow[it] * KK2 + k0 + soff[it], &Af[e * 8]);
            gl2lds(Brow + (size_t)srow[it] * KK2 + k0 + soff[it], &Bf[e * 8]);
        }
        __syncthreads();
#pragma unroll
        for (int kk = 0; kk < 2; ++kk) {
            const int cs = kk ? cs1 : cs0;
            bf16x8 av[4], bv[4], gv[4];
#pragma unroll
            for (int m = 0; m < 4; ++m) av[m] = *(const bf16x8*)&Af[rA[m] + cs];
#pragma unroll
            for (int n = 0; n < 4; ++n) bv[n] = *(const bf16x8*)&Bf[rB[n] + cs];
#pragma unroll
            for (int m = 0; m < 4; ++m) gv[m] = conj_swap(av[m]);
#pragma unroll
            for (int m = 0; m < 4; ++m)
#pragma unroll
                for (int n = 0; n < 4; ++n) {
                    acc_re[m][n] = __builtin_amdgcn_mfma_f32_16x16x32_bf16(av[m], bv[n], acc_re[m][n], 0, 0, 0);
                    acc_im[m][n] = __builtin_amdgcn_mfma_f32_16x16x32_bf16(gv[m], bv[n], acc_im[m][n], 0, 0, 0);
                }
        }
    }

    float* __restrict__ Sb = Sout + (size_t)b * NN * NN;
#pragma unroll
    for (int m = 0; m < 4; ++m) {
#pragma unroll
        for (int reg = 0; reg < 4; ++reg) {
            int r = brow + wr + m * 16 + q * 4 + reg;
            float* __restrict__ rp = Sb + (size_t)r * NN + bcol + wc + fr;
#pragma unroll
            for (int n = 0; n < 4; ++n) {
                float re = acc_re[m][n][reg], im = acc_im[m][n][reg];
                rp[n * 16] = sqrtf(fmaf(re, re, im * im));
            }
        }
    }
    if (brow == bcol) return;

    // mirror store via LDS transpose
#pragma unroll
    for (int p = 0; p < 4; ++p) {
        __syncthreads();
        if ((wave >> 1) == (p >> 1)) {
            const int mbase = (p & 1) * 2;
#pragma unroll
            for (int mm = 0; mm < 2; ++mm) {
                const int m = mbase + mm;
                const int i0 = mm * 16 + q * 4;
#pragma unroll
                for (int reg = 0; reg < 4; ++reg) {
#pragma unroll
                    for (int n = 0; n < 4; ++n) {
                        float re = acc_re[m][n][reg], im = acc_im[m][n][reg];
                        trs[i0 + reg][wc + n * 16 + fr] = sqrtf(fmaf(re, re, im * im));
                    }
                }
            }
        }
        __syncthreads();
        const int j0 = (tid & 7) * 4;
#pragma unroll
        for (int u = 0; u < 4; ++u) {
            const int mr = u * 32 + (tid >> 3);
            float4 v;
            v.x = trs[j0 + 0][mr];
            v.y = trs[j0 + 1][mr];
            v.z = trs[j0 + 2][mr];
            v.w = trs[j0 + 3][mr];
            *(float4*)(Sb + (size_t)(bcol + mr) * NN + brow + p * 32 + j0) = v;
        }
    }
}

// ---------------------------------------------------------------------------
// row softmax of S/2 -> bf16 weights. Max-free: S in [0,1] (normalized rows,
// Cauchy-Schwarz) so exp args are bounded; softmax = exp2(s*CEXP)/rowsum.
__global__ __launch_bounds__(256) void k_softmax(const float* __restrict__ S,
                                                 unsigned short* __restrict__ Wout) {
    __shared__ float red[4];
    const size_t row = blockIdx.x;
    const int tid = threadIdx.x;
    const float4* __restrict__ p4 = (const float4*)(S + row * NN);
    float4 v[4];
    float s = 0.f;
#pragma unroll
    for (int u = 0; u < 4; ++u) {
        v[u] = p4[u * 256 + tid];
        v[u].x = exp2f(v[u].x * CEXP);
        v[u].y = exp2f(v[u].y * CEXP);
        v[u].z = exp2f(v[u].z * CEXP);
        v[u].w = exp2f(v[u].w * CEXP);
        s += (v[u].x + v[u].y) + (v[u].z + v[u].w);
    }
    for (int off = 32; off > 0; off >>= 1) s += __shfl_down(s, off, 64);
    if ((tid & 63) == 0) red[tid >> 6] = s;
    __syncthreads();
    const float rinv = 1.0f / ((red[0] + red[1]) + (red[2] + red[3]));
    ushort4* __restrict__ o4 = (ushort4*)(Wout + row * NN);
#pragma unroll
    for (int u = 0; u < 4; ++u) {
        ushort4 w;
        w.x = f2bf(v[u].x * rinv);
        w.y = f2bf(v[u].y * rinv);
        w.z = f2bf(v[u].z * rinv);
        w.w = f2bf(v[u].w * rinv);
        o4[u * 256 + tid] = w;
    }
}

// ---------------------------------------------------------------------------
// xbT[b][d][t] = bf16(x[b][t][d])  (64x64 tiles through LDS)
__global__ __launch_bounds__(256) void k_xpose(const float* __restrict__ x,
                                               u16* __restrict__ xbT) {
    __shared__ u16 st[64][72];
    const int b = blockIdx.z;
    const int t0 = blockIdx.x * 64;
    const int d0 = blockIdx.y * 64;
    const int tid = threadIdx.x;
#pragma unroll
    for (int u = 0; u < 4; ++u) {
        int idx = tid + u * 256;               // 0..1023
        int tl = idx >> 4, d4 = (idx & 15) * 4;
        float4 v = *(const float4*)(x + ((size_t)(b * NN) + t0 + tl) * DD + d0 + d4);
        st[tl][d4 + 0] = f2bf(v.x);
        st[tl][d4 + 1] = f2bf(v.y);
        st[tl][d4 + 2] = f2bf(v.z);
        st[tl][d4 + 3] = f2bf(v.w);
    }
    __syncthreads();
#pragma unroll
    for (int u = 0; u < 2; ++u) {
        int e = tid + u * 256;                 // 0..511
        int dl = e >> 3, t8 = (e & 7) * 8;
        union { u16 h[8]; uint4 q; } o;
#pragma unroll
        for (int j = 0; j < 8; ++j) o.h[j] = st[t8 + j][dl];
        *(uint4*)(xbT + ((size_t)(b * DD) + d0 + dl) * NN + t0 + t8) = o.q;
    }
}

// ---------------------------------------------------------------------------
// mixed += Ssoft @ x : split-K bf16 MFMA. BM=64, BN=128, KS=4 -> 2048 blocks
// (~8/CU for latency hiding). f32 atomicAdd into memset-zeroed mixed buffer.
__global__ __launch_bounds__(256) void k_mixed_split(const u16* __restrict__ Ws,
                                                     const u16* __restrict__ xbT,
                                                     float* __restrict__ mixed) {
    __shared__ u16 As[64 * 64];
    __shared__ u16 Bs[128 * 64];
    const int b = blockIdx.z;
    const int n4 = blockIdx.x & 3;             // bcol block
    const int ks = blockIdx.x >> 2;            // k slice
    const int brow = blockIdx.y * 64;
    const int bcol = n4 * 128;
    const int tid = threadIdx.x;
    const int lane = tid & 63;
    const int wave = tid >> 6;
    const int wr = (wave >> 1) * 32;
    const int wc = (wave & 1) * 64;
    const int fr = lane & 15;
    const int q  = lane >> 4;
    const int sw = lane & 7;

    const u16* __restrict__ Arow = Ws + (size_t)(b * NN + brow) * NN;
    const u16* __restrict__ Brow = xbT + ((size_t)(b * DD) + bcol) * NN;

    const int cs0 = (q ^ sw) * 8;
    const int cs1 = ((4 + q) ^ sw) * 8;

    f32x4 acc[2][4];
#pragma unroll
    for (int m = 0; m < 2; ++m)
#pragma unroll
        for (int n = 0; n < 4; ++n) acc[m][n] = (f32x4)0.f;

    int rA[2], rB[4];
#pragma unroll
    for (int m = 0; m < 2; ++m) rA[m] = (wr + m * 16 + fr) * 64;
#pragma unroll
    for (int n = 0; n < 4; ++n) rB[n] = (wc + n * 16 + fr) * 64;

    const int kc0 = ks * (NN / 64 / KS);
    const int kc1 = kc0 + (NN / 64 / KS);
    for (int kc = kc0; kc < kc1; ++kc) {
        const int k0 = kc * 64;
        __syncthreads();
#pragma unroll
        for (int it = 0; it < 2; ++it) {        // A: 64 rows x 8 chunks
            int e = tid + it * 256;
            int row = e >> 3, ch = e & 7;
            gl2lds(Arow + (size_t)row * NN + k0 + (ch ^ (row & 7)) * 8, &As[e * 8]);
        }
#pragma unroll
        for (int it = 0; it < 4; ++it) {        // B: 128 rows x 8 chunks
            int e = tid + it * 256;
            int row = e >> 3, ch = e & 7;
            gl2lds(Brow + (size_t)row * NN + k0 + (ch ^ (row & 7)) * 8, &Bs[e * 8]);
        }
        __syncthreads();
#pragma unroll
        for (int kk = 0; kk < 2; ++kk) {
            const int cs = kk ? cs1 : cs0;
            bf16x8 av[2], bv[4];
#pragma unroll
            for (int m = 0; m < 2; ++m) av[m] = *(const bf16x8*)&As[rA[m] + cs];
#pragma unroll
            for (int n = 0; n < 4; ++n) bv[n] = *(const bf16x8*)&Bs[rB[n] + cs];
#pragma unroll
            for (int m = 0; m < 2; ++m)
#pragma unroll
                for (int n = 0; n < 4; ++n)
                    acc[m][n] = __builtin_amdgcn_mfma_f32_16x16x32_bf16(av[m], bv[n], acc[m][n], 0, 0, 0);
        }
    }

    float* __restrict__ ob = mixed + (size_t)b * NN * DD;
#pragma unroll
    for (int m = 0; m < 2; ++m) {
#pragma unroll
        for (int reg = 0; reg < 4; ++reg) {
            int r = brow + wr + m * 16 + q * 4 + reg;
            float* __restrict__ rp = ob + (size_t)r * DD + bcol + wc + fr;
#pragma unroll
            for (int n = 0; n < 4; ++n) atomicAdd(&rp[n * 16], acc[m][n][reg]);
        }
    }
}

// ---------------------------------------------------------------------------
// h = x + 0.3*(mixed - x); LayerNorm(D) * gamma + beta
__global__ __launch_bounds__(256) void k_ln(const float* __restrict__ x,
                                            const float* __restrict__ mixed,
                                            const float* __restrict__ gamma,
                                            const float* __restrict__ beta,
                                            float* __restrict__ out) {
    __shared__ float red[8];
    const size_t row = blockIdx.x;
    const int tid = threadIdx.x;
    const float* __restrict__ xr = x + row * DD;
    const float* __restrict__ mr = mixed + row * DD;
    float x0 = xr[tid], x1 = xr[tid + 256];
    float h0 = fmaf(0.3f, mr[tid] - x0, x0);
    float h1 = fmaf(0.3f, mr[tid + 256] - x1, x1);
    float s = h0 + h1;
    float sq = fmaf(h0, h0, h1 * h1);
    for (int off = 32; off > 0; off >>= 1) {
        s += __shfl_down(s, off, 64);
        sq += __shfl_down(sq, off, 64);
    }
    if ((tid & 63) == 0) { red[tid >> 6] = s; red[4 + (tid >> 6)] = sq; }
    __syncthreads();
    const float mu = ((red[0] + red[1]) + (red[2] + red[3])) * (1.0f / DD);
    const float var = ((red[4] + red[5]) + (red[6] + red[7])) * (1.0f / DD) - mu * mu;
    const float rstd = rsqrtf(var + 1e-5f);
    out[row * DD + tid] = fmaf((h0 - mu) * rstd, gamma[tid], beta[tid]);
    out[row * DD + tid + 256] = fmaf((h1 - mu) * rstd, gamma[tid + 256], beta[tid + 256]);
}

// ---------------------------------------------------------------------------
extern "C" void kernel_launch(void* const* d_in, const int* in_sizes, int n_in,
                              void* d_out, int out_size, void* d_ws, size_t ws_size,
                              hipStream_t stream) {
    const float* x     = (const float*)d_in[0];
    const float* Wspec = (const float*)d_in[1];
    const float* gamma = (const float*)d_in[2];
    const float* beta  = (const float*)d_in[3];
    float* out  = (float*)d_out;                       // [B][N][D]
    float* Sout = out + (size_t)BB * NN * DD;          // [B][N][N]

    char* ws = (char*)d_ws;
    u16*   Mt    = (u16*)(ws + MT_OFF);
    u16*   Xf    = (u16*)(ws + XF_OFF);       // xhat, then normalized Xf
    u32*   XfW   = (u32*)(ws + XF_OFF);
    u16*   xb    = (u16*)(ws + SS_OFF);       // aliased pre-softmax
    float* norms = (float*)(ws + NR_OFF);     // aliased pre-softmax
    u16*   Ssoft = (u16*)(ws + SS_OFF);
    u16*   xbT   = (u16*)(ws + XT_OFF);
    float* mixed = (float*)(ws + MX_OFF);

    hipLaunchKernelGGL(k_zero, dim3(124), dim3(256), 0, stream, norms, Mt);
    hipMemsetAsync(mixed, 0, MX_BYTES, stream);
    hipLaunchKernelGGL(k_build_Mt, dim3(257), dim3(512), 0, stream, Wspec, Mt);
    hipLaunchKernelGGL(k_xcast, dim3(2048), dim3(256), 0, stream, x, xb);
    hipLaunchKernelGGL(k_proj_mfma, dim3(KK2 / 64, (BB * NN) / 128), dim3(256), 0, stream,
                       xb, Mt, Xf, norms);
    hipLaunchKernelGGL(k_normalize, dim3(BB * NN / 8), dim3(256), 0, stream, XfW, norms);
    hipLaunchKernelGGL(k_gram_mfma, dim3(BB * NT), dim3(256), 0, stream, Xf, Sout);
    hipLaunchKernelGGL(k_softmax, dim3(BB * NN), dim3(256), 0, stream, Sout, Ssoft);
    hipLaunchKernelGGL(k_xpose, dim3(NN / 64, DD / 64, BB), dim3(256), 0, stream, x, xbT);
    hipLaunchKernelGGL(k_mixed_split, dim3((DD / 128) * KS, NN / 64, BB), dim3(256), 0, stream,
                       Ssoft, xbT, mixed);
    hipLaunchKernelGGL(k_ln, dim3(BB * NN), dim3(256), 0, stream, x, mixed, gamma, beta, out);
}